// Round 2
// baseline (6233.174 us; speedup 1.0000x reference)
//
#include <hip/hip_runtime.h>

constexpr int NN  = 100000;
constexpr int NE  = 1600000;

// ---------------- small helper kernels ----------------

__global__ void zero_f32(float* __restrict__ p, int n) {
  int i = blockIdx.x * blockDim.x + threadIdx.x;
  if (i < n) p[i] = 0.f;
}

__global__ void count_deg(const int* __restrict__ dst, float* __restrict__ deg, int e) {
  int i = blockIdx.x * blockDim.x + threadIdx.x;
  if (i < e) atomicAdd(&deg[dst[i]], 1.0f);
}

__global__ void make_dinv(float* __restrict__ deg, int n) {
  int i = blockIdx.x * blockDim.x + threadIdx.x;
  if (i < n) deg[i] = rsqrtf(deg[i] + 1.0f);   // +1 for self-loop
}

// cast int32 -> float32 (tail outputs: edges, batch)
__global__ void i2f_k(const int* __restrict__ in, float* __restrict__ out, int n) {
  int i = blockIdx.x * blockDim.x + threadIdx.x;
  if (i < n) out[i] = (float)in[i];
}

// agg[i][:] = x[i][:] * dinv[i]^2 + bgc[:]   (self-loop term + bias folded in)
__global__ void agg_init(const float* __restrict__ xg, const float* __restrict__ dinv,
                         const float* __restrict__ bgc, float* __restrict__ agg, int n) {
  int i = blockIdx.x * blockDim.x + threadIdx.x;   // over n*32 float4s
  if (i >= n * 32) return;
  int node = i >> 5, c = i & 31;
  float di = dinv[node];
  float s  = di * di;
  float4 x = ((const float4*)xg)[i];
  float4 b = ((const float4*)bgc)[c];
  float4 o;
  o.x = x.x * s + b.x; o.y = x.y * s + b.y;
  o.z = x.z * s + b.z; o.w = x.w * s + b.w;
  ((float4*)agg)[i] = o;
}

// agg[dst] += x[src] * dinv[src]*dinv[dst]; one thread = (edge, 8-float chunk)
__global__ __launch_bounds__(256) void scatter_k(
    const int* __restrict__ src, const int* __restrict__ dst,
    const float* __restrict__ dinv, const float* __restrict__ xg,
    float* __restrict__ agg, int e)
{
  long long t = (long long)blockIdx.x * blockDim.x + threadIdx.x;
  int ei = (int)(t >> 4);
  int c  = (int)(t & 15);
  if (ei >= e) return;
  int s = src[ei], d = dst[ei];
  float nm = dinv[s] * dinv[d];
  const float4* xp = (const float4*)(xg + (size_t)s * 128 + c * 8);
  float4 a = xp[0], b = xp[1];
  float* ap = agg + (size_t)d * 128 + c * 8;
  atomicAdd(ap + 0, a.x * nm); atomicAdd(ap + 1, a.y * nm);
  atomicAdd(ap + 2, a.z * nm); atomicAdd(ap + 3, a.w * nm);
  atomicAdd(ap + 4, b.x * nm); atomicAdd(ap + 5, b.y * nm);
  atomicAdd(ap + 6, b.z * nm); atomicAdd(ap + 7, b.w * nm);
}

// ---------------- dense layer: out[N,128] = act( concat(A1[N,K1],A2[N,K2]) @ W + bias ) ----------------
// 256 threads, 64-node tile, micro-tile 8 nodes x 4 feats per thread.
// x-tile stored transposed in LDS (stride 68 floats -> 272B rows, 16B aligned).
// W staged 64 rows at a time (32 KB).
template<int K1, int K2, bool DOELU>
__global__ __launch_bounds__(256) void dense_k(
    const float* __restrict__ A1, const float* __restrict__ A2,
    const float* __restrict__ W, const float* __restrict__ bias,
    float* __restrict__ out, int n)
{
  constexpr int K   = K1 + K2;
  constexpr int NT  = 64;
  constexpr int XST = NT + 4;   // 68 floats = 272 B, multiple of 16 B
  __shared__ __align__(16) float xs[K][XST];
  __shared__ __align__(16) float wb[64][128];

  const int tid = threadIdx.x;
  const int n0  = blockIdx.x * NT;

  // stage A1 (coalesced global reads; LDS write transposed)
  for (int idx = tid; idx < NT * K1; idx += 256) {
    int node = idx / K1, k = idx % K1;
    int g = n0 + node; if (g >= n) g = n - 1;
    xs[k][node] = A1[(size_t)g * K1 + k];
  }
  if (K2 > 0) {
    for (int idx = tid; idx < NT * K2; idx += 256) {
      int node = idx / K2, k = idx % K2;
      int g = n0 + node; if (g >= n) g = n - 1;
      xs[K1 + k][node] = A2[(size_t)g * K2 + k];
    }
  }

  const int jG = tid & 31;   // output cols jG*4 .. +3
  const int nG = tid >> 5;   // nodes nG*8 .. +7

  float acc[8][4];
  float4 bv;
  if (bias) bv = *(const float4*)&bias[jG * 4];
  else { bv.x = bv.y = bv.z = bv.w = 0.f; }
  #pragma unroll
  for (int i = 0; i < 8; ++i) {
    acc[i][0] = bv.x; acc[i][1] = bv.y; acc[i][2] = bv.z; acc[i][3] = bv.w;
  }

  for (int cch = 0; cch < K / 64; ++cch) {
    // stage W chunk [64][128] (coalesced, conflict-free)
    for (int idx = tid; idx < 64 * 128; idx += 256) {
      wb[idx >> 7][idx & 127] = W[(size_t)(cch * 64 + (idx >> 7)) * 128 + (idx & 127)];
    }
    __syncthreads();
    #pragma unroll 8
    for (int kk = 0; kk < 64; ++kk) {
      const float4 xa = *(const float4*)&xs[cch * 64 + kk][nG * 8];
      const float4 xb = *(const float4*)&xs[cch * 64 + kk][nG * 8 + 4];
      const float4 wv = *(const float4*)&wb[kk][jG * 4];
      float xv[8] = {xa.x, xa.y, xa.z, xa.w, xb.x, xb.y, xb.z, xb.w};
      float wvv[4] = {wv.x, wv.y, wv.z, wv.w};
      #pragma unroll
      for (int i = 0; i < 8; ++i)
        #pragma unroll
        for (int j = 0; j < 4; ++j)
          acc[i][j] += xv[i] * wvv[j];
    }
    __syncthreads();
  }

  #pragma unroll
  for (int i = 0; i < 8; ++i) {
    int g = n0 + nG * 8 + i;
    if (g < n) {
      float4 o;
      float v0 = acc[i][0], v1 = acc[i][1], v2 = acc[i][2], v3 = acc[i][3];
      if (DOELU) {
        v0 = v0 > 0.f ? v0 : expm1f(v0);
        v1 = v1 > 0.f ? v1 : expm1f(v1);
        v2 = v2 > 0.f ? v2 : expm1f(v2);
        v3 = v3 > 0.f ? v3 : expm1f(v3);
      }
      o.x = v0; o.y = v1; o.z = v2; o.w = v3;
      *(float4*)&out[(size_t)g * 128 + jG * 4] = o;
    }
  }
}

// ---------------- launch ----------------

extern "C" void kernel_launch(void* const* d_in, const int* in_sizes, int n_in,
                              void* d_out, int out_size, void* d_ws, size_t ws_size,
                              hipStream_t stream) {
  (void)in_sizes; (void)n_in; (void)out_size; (void)ws_size;
  const float* feats = (const float*)d_in[0];
  const int*   edges = (const int*)d_in[1];
  const int*   batch = (const int*)d_in[2];
  const float* W1  = (const float*)d_in[3];
  const float* b1  = (const float*)d_in[4];
  const float* W2  = (const float*)d_in[5];
  const float* b2  = (const float*)d_in[6];
  const float* Wgc = (const float*)d_in[7];
  const float* bgc = (const float*)d_in[8];
  const float* Wc  = (const float*)d_in[9];
  const float* bc  = (const float*)d_in[10];
  float* out = (float*)d_out;

  float* buf0 = (float*)d_ws;                    // h1, later xg (GCN linear out)
  float* buf1 = buf0 + (size_t)NN * 128;         // nfeats
  float* agg  = buf1 + (size_t)NN * 128;         // aggregated messages
  float* deg  = agg  + (size_t)NN * 128;         // deg -> dinv

  const int* esrc = edges;
  const int* edst = edges + NE;

  zero_f32 <<<(NN + 255) / 256, 256, 0, stream>>>(deg, NN);
  count_deg<<<(NE + 255) / 256, 256, 0, stream>>>(edst, deg, NE);
  make_dinv<<<(NN + 255) / 256, 256, 0, stream>>>(deg, NN);

  const int nb = (NN + 63) / 64;
  dense_k<64, 0, true ><<<nb, 256, 0, stream>>>(feats, nullptr, W1, b1, buf0, NN);
  dense_k<128, 0, true ><<<nb, 256, 0, stream>>>(buf0, nullptr, W2, b2, buf1, NN);
  dense_k<128, 64, false><<<nb, 256, 0, stream>>>(buf1, feats, Wgc, nullptr, buf0, NN);

  agg_init<<<(NN * 32 + 255) / 256, 256, 0, stream>>>(buf0, deg, bgc, agg, NN);

  long long sthreads = (long long)NE * 16;
  scatter_k<<<(int)((sthreads + 255) / 256), 256, 0, stream>>>(esrc, edst, deg, buf0, agg, NE);

  dense_k<128, 128, true><<<nb, 256, 0, stream>>>(buf1, agg, Wc, bc, out, NN);

  // tail outputs: edges and batch, converted to float (harness reads d_out as f32)
  size_t off = (size_t)NN * 128;
  i2f_k<<<(2 * NE + 255) / 256, 256, 0, stream>>>(edges, out + off, 2 * NE);
  i2f_k<<<(NN + 255) / 256, 256, 0, stream>>>(batch, out + off + (size_t)2 * NE, NN);
}

// Round 3
// 807.582 us; speedup vs baseline: 7.7183x; 7.7183x over previous
//
#include <hip/hip_runtime.h>

constexpr int NN = 100000;
constexpr int NE = 1600000;

// ---------------- CSR build helpers ----------------

__global__ void zero_i32(int* __restrict__ p, int n) {
  int i = blockIdx.x * blockDim.x + threadIdx.x;
  if (i < n) p[i] = 0;
}

__global__ void count_deg(const int* __restrict__ dst, int* __restrict__ degi, int e) {
  int i = blockIdx.x * blockDim.x + threadIdx.x;
  if (i < e) atomicAdd(&degi[dst[i]], 1);
}

__global__ void make_dinv(const int* __restrict__ degi, float* __restrict__ dinv, int n) {
  int i = blockIdx.x * blockDim.x + threadIdx.x;
  if (i < n) dinv[i] = rsqrtf((float)degi[i] + 1.0f);   // +1 self-loop
}

constexpr int SB = 256;

// per-block inclusive scan
__global__ void scan_blk(const int* __restrict__ in, int* __restrict__ incl,
                         int* __restrict__ bsum, int n) {
  __shared__ int sm[SB];
  int i = blockIdx.x * SB + threadIdx.x;
  int v = (i < n) ? in[i] : 0;
  sm[threadIdx.x] = v;
  __syncthreads();
  for (int off = 1; off < SB; off <<= 1) {
    int t = (threadIdx.x >= off) ? sm[threadIdx.x - off] : 0;
    __syncthreads();
    sm[threadIdx.x] += t;
    __syncthreads();
  }
  if (i < n) incl[i] = sm[threadIdx.x];
  if (threadIdx.x == SB - 1) bsum[blockIdx.x] = sm[SB - 1];
}

// single-block exclusive scan of block sums (nb <= 512)
__global__ void scan_top(int* __restrict__ bsum, int nb) {
  __shared__ int sm[512];
  int t = threadIdx.x;
  int v = (t < nb) ? bsum[t] : 0;
  sm[t] = v;
  __syncthreads();
  for (int off = 1; off < 512; off <<= 1) {
    int u = (t >= off) ? sm[t - off] : 0;
    __syncthreads();
    sm[t] += u;
    __syncthreads();
  }
  if (t < nb) bsum[t] = sm[t] - v;   // exclusive
}

__global__ void scan_add(const int* __restrict__ incl, const int* __restrict__ in,
                         const int* __restrict__ bsum, int* __restrict__ row_off, int n) {
  int i = blockIdx.x * SB + threadIdx.x;
  if (i < n) {
    int off = bsum[blockIdx.x];
    row_off[i] = off + incl[i] - in[i];      // exclusive prefix
    if (i == n - 1) row_off[n] = off + incl[i];
  }
}

__global__ void fill_csr(const int* __restrict__ src, const int* __restrict__ dst,
                         const int* __restrict__ row_off, int* __restrict__ cursor,
                         int* __restrict__ csr, int e) {
  int i = blockIdx.x * blockDim.x + threadIdx.x;
  if (i < e) {
    int d = dst[i];
    int pos = row_off[d] + atomicAdd(&cursor[d], 1);
    csr[pos] = src[i];
  }
}

// cast int32 -> float32 (tail outputs: edges, batch)
__global__ void i2f_k(const int* __restrict__ in, float* __restrict__ out, int n) {
  int i = blockIdx.x * blockDim.x + threadIdx.x;
  if (i < n) out[i] = (float)in[i];
}

// ---------------- GCN aggregate: one wave per node, register accumulation ----------------
__global__ __launch_bounds__(256) void gcn_agg(
    const int* __restrict__ row_off, const int* __restrict__ csr,
    const float* __restrict__ dinv, const float* __restrict__ xg,
    const float* __restrict__ bgc, float* __restrict__ agg, int n)
{
  int w = (int)((blockIdx.x * (unsigned)blockDim.x + threadIdx.x) >> 6);
  int lane = threadIdx.x & 63;
  if (w >= n) return;
  float dd = dinv[w];
  float2 b  = ((const float2*)bgc)[lane];
  float2 xv = ((const float2*)(xg + (size_t)w * 128))[lane];
  float s = dd * dd;
  float ax = xv.x * s + b.x;
  float ay = xv.y * s + b.y;
  int e = row_off[w], end = row_off[w + 1];
  for (; e + 4 <= end; e += 4) {
    int s0 = csr[e], s1 = csr[e + 1], s2 = csr[e + 2], s3 = csr[e + 3];
    float n0 = dinv[s0] * dd, n1 = dinv[s1] * dd, n2 = dinv[s2] * dd, n3 = dinv[s3] * dd;
    float2 v0 = ((const float2*)(xg + (size_t)s0 * 128))[lane];
    float2 v1 = ((const float2*)(xg + (size_t)s1 * 128))[lane];
    float2 v2 = ((const float2*)(xg + (size_t)s2 * 128))[lane];
    float2 v3 = ((const float2*)(xg + (size_t)s3 * 128))[lane];
    ax += v0.x * n0 + v1.x * n1 + v2.x * n2 + v3.x * n3;
    ay += v0.y * n0 + v1.y * n1 + v2.y * n2 + v3.y * n3;
  }
  for (; e < end; ++e) {
    int s0 = csr[e];
    float n0 = dinv[s0] * dd;
    float2 v0 = ((const float2*)(xg + (size_t)s0 * 128))[lane];
    ax += v0.x * n0; ay += v0.y * n0;
  }
  float2 o; o.x = ax; o.y = ay;
  ((float2*)(agg + (size_t)w * 128))[lane] = o;
}

// ---------------- dense layer (unchanged from round 2) ----------------
template<int K1, int K2, bool DOELU>
__global__ __launch_bounds__(256) void dense_k(
    const float* __restrict__ A1, const float* __restrict__ A2,
    const float* __restrict__ W, const float* __restrict__ bias,
    float* __restrict__ out, int n)
{
  constexpr int K   = K1 + K2;
  constexpr int NT  = 64;
  constexpr int XST = NT + 4;
  __shared__ __align__(16) float xs[K][XST];
  __shared__ __align__(16) float wb[64][128];

  const int tid = threadIdx.x;
  const int n0  = blockIdx.x * NT;

  for (int idx = tid; idx < NT * K1; idx += 256) {
    int node = idx / K1, k = idx % K1;
    int g = n0 + node; if (g >= n) g = n - 1;
    xs[k][node] = A1[(size_t)g * K1 + k];
  }
  if (K2 > 0) {
    for (int idx = tid; idx < NT * K2; idx += 256) {
      int node = idx / K2, k = idx % K2;
      int g = n0 + node; if (g >= n) g = n - 1;
      xs[K1 + k][node] = A2[(size_t)g * K2 + k];
    }
  }

  const int jG = tid & 31;
  const int nG = tid >> 5;

  float acc[8][4];
  float4 bv;
  if (bias) bv = *(const float4*)&bias[jG * 4];
  else { bv.x = bv.y = bv.z = bv.w = 0.f; }
  #pragma unroll
  for (int i = 0; i < 8; ++i) {
    acc[i][0] = bv.x; acc[i][1] = bv.y; acc[i][2] = bv.z; acc[i][3] = bv.w;
  }

  for (int cch = 0; cch < K / 64; ++cch) {
    for (int idx = tid; idx < 64 * 128; idx += 256) {
      wb[idx >> 7][idx & 127] = W[(size_t)(cch * 64 + (idx >> 7)) * 128 + (idx & 127)];
    }
    __syncthreads();
    #pragma unroll 8
    for (int kk = 0; kk < 64; ++kk) {
      const float4 xa = *(const float4*)&xs[cch * 64 + kk][nG * 8];
      const float4 xb = *(const float4*)&xs[cch * 64 + kk][nG * 8 + 4];
      const float4 wv = *(const float4*)&wb[kk][jG * 4];
      float xv[8] = {xa.x, xa.y, xa.z, xa.w, xb.x, xb.y, xb.z, xb.w};
      float wvv[4] = {wv.x, wv.y, wv.z, wv.w};
      #pragma unroll
      for (int i = 0; i < 8; ++i)
        #pragma unroll
        for (int j = 0; j < 4; ++j)
          acc[i][j] += xv[i] * wvv[j];
    }
    __syncthreads();
  }

  #pragma unroll
  for (int i = 0; i < 8; ++i) {
    int g = n0 + nG * 8 + i;
    if (g < n) {
      float4 o;
      float v0 = acc[i][0], v1 = acc[i][1], v2 = acc[i][2], v3 = acc[i][3];
      if (DOELU) {
        v0 = v0 > 0.f ? v0 : expm1f(v0);
        v1 = v1 > 0.f ? v1 : expm1f(v1);
        v2 = v2 > 0.f ? v2 : expm1f(v2);
        v3 = v3 > 0.f ? v3 : expm1f(v3);
      }
      o.x = v0; o.y = v1; o.z = v2; o.w = v3;
      *(float4*)&out[(size_t)g * 128 + jG * 4] = o;
    }
  }
}

// ---------------- launch ----------------

extern "C" void kernel_launch(void* const* d_in, const int* in_sizes, int n_in,
                              void* d_out, int out_size, void* d_ws, size_t ws_size,
                              hipStream_t stream) {
  (void)in_sizes; (void)n_in; (void)out_size; (void)ws_size;
  const float* feats = (const float*)d_in[0];
  const int*   edges = (const int*)d_in[1];
  const int*   batch = (const int*)d_in[2];
  const float* W1  = (const float*)d_in[3];
  const float* b1  = (const float*)d_in[4];
  const float* W2  = (const float*)d_in[5];
  const float* b2  = (const float*)d_in[6];
  const float* Wgc = (const float*)d_in[7];
  const float* bgc = (const float*)d_in[8];
  const float* Wc  = (const float*)d_in[9];
  const float* bc  = (const float*)d_in[10];
  float* out = (float*)d_out;

  // workspace: 3 big f32 buffers + dinv (same footprint as round 2)
  float* buf0 = (float*)d_ws;                    // h1, later xg (GCN linear out)
  float* buf1 = buf0 + (size_t)NN * 128;         // nfeats
  float* agg  = buf1 + (size_t)NN * 128;         // aggregated messages
  float* dinv = agg  + (size_t)NN * 128;         // [NN]

  // CSR scratch in the FRONT of d_out (dead before final dense_k writes it)
  int* scr     = (int*)d_out;
  int* csr_src = scr;                   // [NE]
  int* row_off = csr_src + NE;          // [NN+1]
  int* degi    = row_off + NN + 1;      // [NN]
  int* incl    = degi + NN;             // [NN]
  int* cursor  = incl + NN;             // [NN]
  int* bsum    = cursor + NN;           // [512]

  const int* esrc = edges;
  const int* edst = edges + NE;

  const int nbN = (NN + 255) / 256;
  const int nbE = (NE + 255) / 256;
  const int nsc = (NN + SB - 1) / SB;   // 391

  // --- CSR build ---
  zero_i32 <<<nbN, 256, 0, stream>>>(degi, NN);
  zero_i32 <<<nbN, 256, 0, stream>>>(cursor, NN);
  count_deg<<<nbE, 256, 0, stream>>>(edst, degi, NE);
  make_dinv<<<nbN, 256, 0, stream>>>(degi, dinv, NN);
  scan_blk <<<nsc, SB, 0, stream>>>(degi, incl, bsum, NN);
  scan_top <<<1, 512, 0, stream>>>(bsum, nsc);
  scan_add <<<nsc, SB, 0, stream>>>(incl, degi, bsum, row_off, NN);
  fill_csr <<<nbE, 256, 0, stream>>>(esrc, edst, row_off, cursor, csr_src, NE);

  // --- dense chain ---
  const int nb = (NN + 63) / 64;
  dense_k<64, 0, true ><<<nb, 256, 0, stream>>>(feats, nullptr, W1, b1, buf0, NN);
  dense_k<128, 0, true ><<<nb, 256, 0, stream>>>(buf0, nullptr, W2, b2, buf1, NN);
  dense_k<128, 64, false><<<nb, 256, 0, stream>>>(buf1, feats, Wgc, nullptr, buf0, NN);

  // --- GCN aggregate: one wave per node ---
  long long wthreads = (long long)NN * 64;
  gcn_agg<<<(int)((wthreads + 255) / 256), 256, 0, stream>>>(
      row_off, csr_src, dinv, buf0, bgc, agg, NN);

  // --- output layer (overwrites CSR scratch region of d_out) ---
  dense_k<128, 128, true><<<nb, 256, 0, stream>>>(buf1, agg, Wc, bc, out, NN);

  // tail outputs: edges and batch, as float
  size_t off = (size_t)NN * 128;
  i2f_k<<<(2 * NE + 255) / 256, 256, 0, stream>>>(edges, out + off, 2 * NE);
  i2f_k<<<(NN + 255) / 256, 256, 0, stream>>>(batch, out + off + (size_t)2 * NE, NN);
}

// Round 4
// 438.368 us; speedup vs baseline: 14.2190x; 1.8422x over previous
//
#include <hip/hip_runtime.h>
#include <hip/hip_bf16.h>

constexpr int NN = 100000;
constexpr int NE = 1600000;

typedef __bf16 bf16_t;
typedef bf16_t bf16x8 __attribute__((ext_vector_type(8)));
typedef bf16_t bf16x4 __attribute__((ext_vector_type(4)));
typedef bf16_t bf16x2 __attribute__((ext_vector_type(2)));
typedef float  f32x4  __attribute__((ext_vector_type(4)));

// ---------------- CSR build helpers ----------------

__global__ void zero_i32(int* __restrict__ p, int n) {
  int i = blockIdx.x * blockDim.x + threadIdx.x;
  if (i < n) p[i] = 0;
}

__global__ void count_deg(const int* __restrict__ dst, int* __restrict__ degi, int e) {
  int i = blockIdx.x * blockDim.x + threadIdx.x;
  if (i < e) atomicAdd(&degi[dst[i]], 1);
}

__global__ void make_dinv(const int* __restrict__ degi, float* __restrict__ dinv, int n) {
  int i = blockIdx.x * blockDim.x + threadIdx.x;
  if (i < n) dinv[i] = rsqrtf((float)degi[i] + 1.0f);   // +1 self-loop
}

constexpr int SB = 256;

__global__ void scan_blk(const int* __restrict__ in, int* __restrict__ incl,
                         int* __restrict__ bsum, int n) {
  __shared__ int sm[SB];
  int i = blockIdx.x * SB + threadIdx.x;
  int v = (i < n) ? in[i] : 0;
  sm[threadIdx.x] = v;
  __syncthreads();
  for (int off = 1; off < SB; off <<= 1) {
    int t = (threadIdx.x >= off) ? sm[threadIdx.x - off] : 0;
    __syncthreads();
    sm[threadIdx.x] += t;
    __syncthreads();
  }
  if (i < n) incl[i] = sm[threadIdx.x];
  if (threadIdx.x == SB - 1) bsum[blockIdx.x] = sm[SB - 1];
}

__global__ void scan_top(int* __restrict__ bsum, int nb) {
  __shared__ int sm[512];
  int t = threadIdx.x;
  int v = (t < nb) ? bsum[t] : 0;
  sm[t] = v;
  __syncthreads();
  for (int off = 1; off < 512; off <<= 1) {
    int u = (t >= off) ? sm[t - off] : 0;
    __syncthreads();
    sm[t] += u;
    __syncthreads();
  }
  if (t < nb) bsum[t] = sm[t] - v;   // exclusive
}

__global__ void scan_add(const int* __restrict__ incl, const int* __restrict__ in,
                         const int* __restrict__ bsum, int* __restrict__ row_off, int n) {
  int i = blockIdx.x * SB + threadIdx.x;
  if (i < n) {
    int off = bsum[blockIdx.x];
    row_off[i] = off + incl[i] - in[i];
    if (i == n - 1) row_off[n] = off + incl[i];
  }
}

__global__ void fill_csr(const int* __restrict__ src, const int* __restrict__ dst,
                         const int* __restrict__ row_off, int* __restrict__ cursor,
                         int* __restrict__ csr, int e) {
  int i = blockIdx.x * blockDim.x + threadIdx.x;
  if (i < e) {
    int d = dst[i];
    int pos = row_off[d] + atomicAdd(&cursor[d], 1);
    csr[pos] = src[i];
  }
}

__global__ void i2f_k(const int* __restrict__ in, float* __restrict__ out, int n) {
  int i = blockIdx.x * blockDim.x + threadIdx.x;
  if (i < n) out[i] = (float)in[i];
}

// f32 -> bf16, 4 at a time
__global__ void f2b_k(const float* __restrict__ in, bf16_t* __restrict__ out, int n4) {
  int i = blockIdx.x * blockDim.x + threadIdx.x;
  if (i < n4) {
    float4 v = ((const float4*)in)[i];
    bf16x4 o;
    o.x = (bf16_t)v.x; o.y = (bf16_t)v.y; o.z = (bf16_t)v.z; o.w = (bf16_t)v.w;
    ((bf16x4*)out)[i] = o;
  }
}

// shuffle W[K][128] f32 into MFMA B-fragment order, bf16:
// Wf[((kt*8 + c)*64 + lane)*8 + j] = W[kt*32 + (lane>>4)*8 + j][c*16 + (lane&15)]
__global__ void wprep(const float* __restrict__ W, bf16_t* __restrict__ Wf, int total) {
  int idx = blockIdx.x * blockDim.x + threadIdx.x;
  if (idx >= total) return;
  int j    = idx & 7;
  int lane = (idx >> 3) & 63;
  int c    = (idx >> 9) & 7;
  int kt   = idx >> 12;
  int k    = kt * 32 + (lane >> 4) * 8 + j;
  int col  = c * 16 + (lane & 15);
  Wf[idx] = (bf16_t)W[(size_t)k * 128 + col];
}

// ---------------- MFMA dense ----------------
// out[N,128] = act( concat(A1[N,K1],A2[N,K2]) @ W + bias )
// 256 threads = 4 waves; each wave: 32 rows x 128 cols. No LDS.
template<int K1, int K2, bool DOELU, bool OUTF32>
__global__ __launch_bounds__(256) void mf_dense(
    const bf16_t* __restrict__ A1, const bf16_t* __restrict__ A2,
    const bf16_t* __restrict__ Wf, const float* __restrict__ bias,
    bf16_t* __restrict__ outb, float* __restrict__ outf, int n)
{
  constexpr int K   = K1 + K2;
  constexpr int NKT = K / 32;
  static_assert(K1 % 32 == 0, "K-step must not straddle A1/A2");

  const int tid  = threadIdx.x;
  const int wv   = tid >> 6;
  const int lane = tid & 63;
  const int r    = lane & 15;
  const int kb   = lane >> 4;
  const int row0 = blockIdx.x * 128 + wv * 32;

  f32x4 acc[2][8];
  #pragma unroll
  for (int i = 0; i < 2; ++i)
    #pragma unroll
    for (int c = 0; c < 8; ++c)
      acc[i][c] = (f32x4){0.f, 0.f, 0.f, 0.f};

  const bf16x8* WfV = (const bf16x8*)Wf;

  #pragma unroll
  for (int kt = 0; kt < NKT; ++kt) {
    const int kofs = kt * 32 + kb * 8;
    bf16x8 a[2];
    #pragma unroll
    for (int i = 0; i < 2; ++i) {
      int row = row0 + i * 16 + r;
      if (row >= n) row = n - 1;
      const bf16_t* ap;
      if (K2 == 0 || kofs < K1) ap = A1 + (size_t)row * K1 + kofs;
      else                      ap = A2 + (size_t)row * K2 + (kofs - K1);
      a[i] = *(const bf16x8*)ap;
    }
    #pragma unroll
    for (int c = 0; c < 8; ++c) {
      bf16x8 b = WfV[(kt * 8 + c) * 64 + lane];
      acc[0][c] = __builtin_amdgcn_mfma_f32_16x16x32_bf16(a[0], b, acc[0][c], 0, 0, 0);
      acc[1][c] = __builtin_amdgcn_mfma_f32_16x16x32_bf16(a[1], b, acc[1][c], 0, 0, 0);
    }
  }

  // C/D layout: col = c*16 + (lane&15), row = rowtile + (lane>>4)*4 + q
  #pragma unroll
  for (int c = 0; c < 8; ++c) {
    const int col = c * 16 + r;
    const float bv = bias ? bias[col] : 0.f;
    #pragma unroll
    for (int i = 0; i < 2; ++i) {
      #pragma unroll
      for (int q = 0; q < 4; ++q) {
        int row = row0 + i * 16 + kb * 4 + q;
        if (row < n) {
          float v = acc[i][c][q] + bv;
          if (DOELU) v = v > 0.f ? v : expm1f(v);
          if (OUTF32) outf[(size_t)row * 128 + col] = v;
          else        outb[(size_t)row * 128 + col] = (bf16_t)v;
        }
      }
    }
  }
}

// ---------------- GCN aggregate: one wave per node, bf16 in/out, fp32 accum ----------------
__global__ __launch_bounds__(256) void gcn_agg_b(
    const int* __restrict__ row_off, const int* __restrict__ csr,
    const float* __restrict__ dinv, const bf16_t* __restrict__ xg,
    const float* __restrict__ bgc, bf16_t* __restrict__ agg, int n)
{
  int w = (int)((blockIdx.x * (unsigned)blockDim.x + threadIdx.x) >> 6);
  int lane = threadIdx.x & 63;
  if (w >= n) return;
  float dd = dinv[w];
  float2 b = ((const float2*)bgc)[lane];
  bf16x2 xv = ((const bf16x2*)(xg + (size_t)w * 128))[lane];
  float s = dd * dd;
  float ax = (float)xv.x * s + b.x;
  float ay = (float)xv.y * s + b.y;
  int e = row_off[w], end = row_off[w + 1];
  for (; e + 4 <= end; e += 4) {
    int s0 = csr[e], s1 = csr[e + 1], s2 = csr[e + 2], s3 = csr[e + 3];
    float n0 = dinv[s0] * dd, n1 = dinv[s1] * dd, n2 = dinv[s2] * dd, n3 = dinv[s3] * dd;
    bf16x2 v0 = ((const bf16x2*)(xg + (size_t)s0 * 128))[lane];
    bf16x2 v1 = ((const bf16x2*)(xg + (size_t)s1 * 128))[lane];
    bf16x2 v2 = ((const bf16x2*)(xg + (size_t)s2 * 128))[lane];
    bf16x2 v3 = ((const bf16x2*)(xg + (size_t)s3 * 128))[lane];
    ax += (float)v0.x * n0 + (float)v1.x * n1 + (float)v2.x * n2 + (float)v3.x * n3;
    ay += (float)v0.y * n0 + (float)v1.y * n1 + (float)v2.y * n2 + (float)v3.y * n3;
  }
  for (; e < end; ++e) {
    int s0 = csr[e];
    float n0 = dinv[s0] * dd;
    bf16x2 v0 = ((const bf16x2*)(xg + (size_t)s0 * 128))[lane];
    ax += (float)v0.x * n0; ay += (float)v0.y * n0;
  }
  bf16x2 o;
  o.x = (bf16_t)ax; o.y = (bf16_t)ay;
  ((bf16x2*)(agg + (size_t)w * 128))[lane] = o;
}

// ---------------- launch ----------------

extern "C" void kernel_launch(void* const* d_in, const int* in_sizes, int n_in,
                              void* d_out, int out_size, void* d_ws, size_t ws_size,
                              hipStream_t stream) {
  (void)in_sizes; (void)n_in; (void)out_size; (void)ws_size;
  const float* feats = (const float*)d_in[0];
  const int*   edges = (const int*)d_in[1];
  const int*   batch = (const int*)d_in[2];
  const float* W1  = (const float*)d_in[3];
  const float* b1  = (const float*)d_in[4];
  const float* W2  = (const float*)d_in[5];
  const float* b2  = (const float*)d_in[6];
  const float* Wgc = (const float*)d_in[7];
  const float* bgc = (const float*)d_in[8];
  const float* Wc  = (const float*)d_in[9];
  const float* bc  = (const float*)d_in[10];
  float* out = (float*)d_out;

  // workspace layout (bf16 activations)
  bf16_t* featsb = (bf16_t*)d_ws;                      // [NN*64]
  bf16_t* h1b    = featsb + (size_t)NN * 64;           // [NN*128]
  bf16_t* h2b    = h1b    + (size_t)NN * 128;          // [NN*128] (nfeats)
  bf16_t* xgb    = h2b    + (size_t)NN * 128;          // [NN*128] (GCN linear out)
  bf16_t* aggb   = xgb    + (size_t)NN * 128;          // [NN*128]
  float*  dinv   = (float*)(aggb + (size_t)NN * 128);  // [NN]
  bf16_t* w1f    = (bf16_t*)(dinv + NN);               // [64*128]
  bf16_t* w2f    = w1f  + 64  * 128;                   // [128*128]
  bf16_t* wgcf   = w2f  + 128 * 128;                   // [192*128]
  bf16_t* wcf    = wgcf + 192 * 128;                   // [256*128]

  // CSR scratch in the FRONT of d_out (dead before final mf_dense writes it)
  int* scr     = (int*)d_out;
  int* csr_src = scr;                   // [NE]
  int* row_off = csr_src + NE;          // [NN+1]
  int* degi    = row_off + NN + 1;      // [NN]
  int* incl    = degi + NN;             // [NN]
  int* cursor  = incl + NN;             // [NN]
  int* bsum    = cursor + NN;           // [512]

  const int* esrc = edges;
  const int* edst = edges + NE;

  const int nbN = (NN + 255) / 256;
  const int nbE = (NE + 255) / 256;
  const int nsc = (NN + SB - 1) / SB;

  // --- CSR build ---
  zero_i32 <<<nbN, 256, 0, stream>>>(degi, NN);
  zero_i32 <<<nbN, 256, 0, stream>>>(cursor, NN);
  count_deg<<<nbE, 256, 0, stream>>>(edst, degi, NE);
  make_dinv<<<nbN, 256, 0, stream>>>(degi, dinv, NN);
  scan_blk <<<nsc, SB, 0, stream>>>(degi, incl, bsum, NN);
  scan_top <<<1, 512, 0, stream>>>(bsum, nsc);
  scan_add <<<nsc, SB, 0, stream>>>(incl, degi, bsum, row_off, NN);
  fill_csr <<<nbE, 256, 0, stream>>>(esrc, edst, row_off, cursor, csr_src, NE);

  // --- dtype prep ---
  f2b_k<<<(NN * 64 / 4 + 255) / 256, 256, 0, stream>>>(feats, featsb, NN * 64 / 4);
  wprep<<<(64  * 128 + 255) / 256, 256, 0, stream>>>(W1,  w1f,  64  * 128);
  wprep<<<(128 * 128 + 255) / 256, 256, 0, stream>>>(W2,  w2f,  128 * 128);
  wprep<<<(192 * 128 + 255) / 256, 256, 0, stream>>>(Wgc, wgcf, 192 * 128);
  wprep<<<(256 * 128 + 255) / 256, 256, 0, stream>>>(Wc,  wcf,  256 * 128);

  // --- dense chain on MFMA ---
  const int nb = (NN + 127) / 128;
  mf_dense<64, 0, true, false><<<nb, 256, 0, stream>>>(featsb, nullptr, w1f, b1, h1b, nullptr, NN);
  mf_dense<128, 0, true, false><<<nb, 256, 0, stream>>>(h1b, nullptr, w2f, b2, h2b, nullptr, NN);
  mf_dense<128, 64, false, false><<<nb, 256, 0, stream>>>(h2b, featsb, wgcf, nullptr, xgb, nullptr, NN);

  // --- GCN aggregate ---
  long long wthreads = (long long)NN * 64;
  gcn_agg_b<<<(int)((wthreads + 255) / 256), 256, 0, stream>>>(
      row_off, csr_src, dinv, xgb, bgc, aggb, NN);

  // --- output layer (fp32 into d_out, overwrites CSR scratch) ---
  mf_dense<128, 128, true, true><<<nb, 256, 0, stream>>>(h2b, aggb, wcf, bc, nullptr, out, NN);

  // tail outputs: edges and batch, as float
  size_t off = (size_t)NN * 128;
  i2f_k<<<(2 * NE + 255) / 256, 256, 0, stream>>>(edges, out + off, 2 * NE);
  i2f_k<<<(NN + 255) / 256, 256, 0, stream>>>(batch, out + off + (size_t)2 * NE, NN);
}